// Round 1
// baseline (99.385 us; speedup 1.0000x reference)
//
#include <hip/hip_runtime.h>
#include <cfloat>

// Problem constants (fixed by the reference):
//   x: (B=256, T=150, J=25, 3) fp32;  out: (B, J, 9) fp32
//   per frame: pairwise dists among 25 joints; per joint the 4 smallest
//   non-self distances d1<=d2<=d3<=d4 feed features for k=2,3,4:
//   [avg_k, std_k(ddof=1), min_k] each, concatenated, then mean over T.
#define NB 256
#define NT 150
#define NJ 25
#define CHUNK 10            // frames per wave
#define CPB (NT / CHUNK)    // 15 chunks per batch element
#define WAVES 4
#define BLOCKSZ 256

__global__ void zero_kernel(float* __restrict__ out, int n) {
    int i = blockIdx.x * blockDim.x + threadIdx.x;
    if (i < n) out[i] = 0.0f;
}

// One wave handles CHUNK frames of one batch element, two frames at a time
// (lanes 0..31 -> even frame of the pair, lanes 32..63 -> odd frame).
// Lane jj (<25) owns joint jj: selects the 4 smallest non-self SQUARED
// distances with a branchless sorted-insert network, sqrts only those 4,
// accumulates the 9 per-frame features, and finally atomically adds the
// (1/T)-scaled partial into the output.
__global__ __launch_bounds__(BLOCKSZ) void knn_feat_kernel(
        const float* __restrict__ x, float* __restrict__ out) {
    __shared__ float4 spos[WAVES][2][NJ];   // padded float4 -> ds_read_b128 broadcast

    const int tid  = threadIdx.x;
    const int wave = tid >> 6;
    const int lane = tid & 63;
    const int half = lane >> 5;      // which frame of the pair
    const int jj   = lane & 31;      // joint id within half
    const bool act = (jj < NJ);
    const int  jc  = act ? jj : NJ - 1;   // clamp for in-bounds loads

    const int gw = blockIdx.x * WAVES + wave;   // global wave id in [0, NB*CPB)
    const int b  = gw / CPB;
    const int c  = gw - b * CPB;
    const int t0 = c * CHUNK;

    float acc[9];
#pragma unroll
    for (int f = 0; f < 9; ++f) acc[f] = 0.0f;

    for (int p = 0; p < CHUNK / 2; ++p) {
        const int t = t0 + 2 * p + half;
        const float* fp = x + (size_t)(((b * NT + t) * NJ + jc) * 3);
        const float px = fp[0], py = fp[1], pz = fp[2];
        if (act) spos[wave][half][jj] = make_float4(px, py, pz, 0.0f);
        __syncthreads();   // uniform across block: all waves run same trip counts

        // 4 smallest non-self squared distances (sorted ascending b0..b3)
        float b0 = FLT_MAX, b1 = FLT_MAX, b2 = FLT_MAX, b3 = FLT_MAX;
#pragma unroll
        for (int i = 0; i < NJ; ++i) {
            const float4 q = spos[wave][half][i];
            const float dx = q.x - px, dy = q.y - py, dz = q.z - pz;
            float d2 = dx * dx + dy * dy + dz * dz;
            d2 = (i == jj) ? FLT_MAX : d2;    // exclude self (dist 0)
            float m;
            m = fminf(b0, d2); d2 = fmaxf(b0, d2); b0 = m;
            m = fminf(b1, d2); d2 = fmaxf(b1, d2); b1 = m;
            m = fminf(b2, d2); d2 = fmaxf(b2, d2); b2 = m;
            m = fminf(b3, d2); d2 = fmaxf(b3, d2); b3 = m;
        }
        __syncthreads();   // WAR: before next pair overwrites spos

        const float d1 = sqrtf(b0), d2r = sqrtf(b1), d3 = sqrtf(b2), d4 = sqrtf(b3);

        // k=2 : avg, std(ddof=1), min
        const float s2 = d1 + d2r, a2 = 0.5f * s2;
        float e1 = d1 - a2, e2 = d2r - a2;
        const float std2 = sqrtf(e1 * e1 + e2 * e2);   // /(2-1)
        acc[0] += a2; acc[1] += std2; acc[2] += d1;
        // k=3
        const float s3 = s2 + d3, a3 = s3 * (1.0f / 3.0f);
        e1 = d1 - a3; e2 = d2r - a3; float e3 = d3 - a3;
        const float std3 = sqrtf((e1 * e1 + e2 * e2 + e3 * e3) * 0.5f);
        acc[3] += a3; acc[4] += std3; acc[5] += d1;
        // k=4
        const float s4 = s3 + d4, a4 = 0.25f * s4;
        e1 = d1 - a4; e2 = d2r - a4; e3 = d3 - a4; const float e4 = d4 - a4;
        const float std4 = sqrtf((e1 * e1 + e2 * e2 + e3 * e3 + e4 * e4) * (1.0f / 3.0f));
        acc[6] += a4; acc[7] += std4; acc[8] += d1;
    }

    // combine the two half-wave frame streams (even+odd frames)
#pragma unroll
    for (int f = 0; f < 9; ++f) acc[f] += __shfl_xor(acc[f], 32, 64);

    if (act && half == 0) {
        float* op = out + (size_t)((b * NJ + jj) * 9);
        const float sc = 1.0f / (float)NT;
#pragma unroll
        for (int f = 0; f < 9; ++f) atomicAdd(op + f, acc[f] * sc);
    }
}

extern "C" void kernel_launch(void* const* d_in, const int* in_sizes, int n_in,
                              void* d_out, int out_size, void* d_ws, size_t ws_size,
                              hipStream_t stream) {
    const float* x = (const float*)d_in[0];
    float* out = (float*)d_out;

    // out is poisoned before every launch -> zero it (atomic accumulation target)
    zero_kernel<<<(out_size + BLOCKSZ - 1) / BLOCKSZ, BLOCKSZ, 0, stream>>>(out, out_size);

    const int total_waves = NB * CPB;            // 3840
    const int blocks = total_waves / WAVES;      // 960
    knn_feat_kernel<<<blocks, BLOCKSZ, 0, stream>>>(x, out);
}

// Round 2
// 78.181 us; speedup vs baseline: 1.2712x; 1.2712x over previous
//
#include <hip/hip_runtime.h>
#include <cfloat>

// x: (B=256, T=150, J=25, 3) fp32 -> out: (B, J, 9) fp32
// Per frame: 25x25 pairwise dists, per joint the 4 smallest non-self
// distances d1<=d2<=d3<=d4 feed [avg,std(ddof=1),min] for k=2,3,4; mean over T.
#define NB 256
#define NT 150
#define NJ 25
#define CHUNK 10            // frames per wave
#define CPB (NT / CHUNK)    // 15 chunks per batch element
#define WAVES 4
#define BLOCKSZ 256
#define NW (NB * CPB)       // 3840 partial slots, 225 floats each -> 3.456 MB ws

// sorted ascending insert of v into (s0<=s1<=s2<=s3); only min kept at last stage
#define INS4(s0, s1, s2, s3, v)                                   \
    {                                                             \
        float m_;                                                 \
        m_ = fminf(s0, v); v = fmaxf(s0, v); s0 = m_;             \
        m_ = fminf(s1, v); v = fmaxf(s1, v); s1 = m_;             \
        m_ = fminf(s2, v); v = fmaxf(s2, v); s2 = m_;             \
        s3 = fminf(s3, v);                                        \
    }

__global__ __launch_bounds__(BLOCKSZ) void knn_partial_kernel(
        const float* __restrict__ x, float* __restrict__ ws) {
    __shared__ float4 spos[WAVES][CHUNK][NJ];

    const int tid  = threadIdx.x;
    const int wave = tid >> 6;
    const int lane = tid & 63;
    const int half = lane >> 5;     // which frame of each pair
    const int jj   = lane & 31;     // joint id within half
    const bool act = (jj < NJ);

    const int gw = blockIdx.x * WAVES + wave;   // [0, NW)
    const int b  = gw / CPB;
    const int c  = gw - b * CPB;
    const int t0 = c * CHUNK;

    // ---- stage the whole chunk (10 frames x 25 joints) packed->float4, once ----
    const float* src = x + (size_t)(b * NT + t0) * NJ * 3;
    for (int p = lane; p < CHUNK * NJ; p += 64) {
        const int f = p / NJ;
        const int j = p - f * NJ;
        const float* s = src + p * 3;
        spos[wave][f][j] = make_float4(s[0], s[1], s[2], 0.0f);
    }
    __syncthreads();   // single barrier; LDS is read-only afterwards

    float acc[9];
#pragma unroll
    for (int f = 0; f < 9; ++f) acc[f] = 0.0f;

    for (int p = 0; p < CHUNK / 2; ++p) {
        const int fr = 2 * p + half;

        // own position (per-lane address, one read)
        const float4 own = spos[wave][fr][act ? jj : 0];

        // batch-load the whole frame into registers (static indices -> VGPRs,
        // 25 outstanding ds_read_b128, one waitcnt)
        float4 q[NJ];
#pragma unroll
        for (int i = 0; i < NJ; ++i) q[i] = spos[wave][fr][i];

        // two parallel sorted-4 chains over squared distances
        float a0 = FLT_MAX, a1 = FLT_MAX, a2 = FLT_MAX, a3 = FLT_MAX;
        float e0 = FLT_MAX, e1 = FLT_MAX, e2 = FLT_MAX, e3 = FLT_MAX;
#pragma unroll
        for (int i = 0; i < 13; ++i) {
            const float dx = q[i].x - own.x, dy = q[i].y - own.y, dz = q[i].z - own.z;
            float d2 = dx * dx + dy * dy + dz * dz;
            d2 = (i == jj) ? FLT_MAX : d2;     // exclude self
            INS4(a0, a1, a2, a3, d2);
        }
#pragma unroll
        for (int i = 13; i < NJ; ++i) {
            const float dx = q[i].x - own.x, dy = q[i].y - own.y, dz = q[i].z - own.z;
            float d2 = dx * dx + dy * dy + dz * dz;
            d2 = (i == jj) ? FLT_MAX : d2;
            INS4(e0, e1, e2, e3, d2);
        }
        // bitonic merge: 4 smallest of (a ++ reverse(e)), then sort the bitonic 4
        const float l0 = fminf(a0, e3), l1 = fminf(a1, e2);
        const float l2 = fminf(a2, e1), l3 = fminf(a3, e0);
        const float m0 = fminf(l0, l2), m2 = fmaxf(l0, l2);
        const float m1 = fminf(l1, l3), m3 = fmaxf(l1, l3);
        const float r0 = fminf(m0, m1), r1 = fmaxf(m0, m1);
        const float r2 = fminf(m2, m3), r3 = fmaxf(m2, m3);

        const float d1 = sqrtf(r0), d2r = sqrtf(r1), d3 = sqrtf(r2), d4 = sqrtf(r3);

        // k=2
        const float s2 = d1 + d2r, a2f = 0.5f * s2;
        float u1 = d1 - a2f, u2 = d2r - a2f;
        acc[0] += a2f; acc[1] += sqrtf(u1 * u1 + u2 * u2); acc[2] += d1;
        // k=3
        const float s3 = s2 + d3, a3f = s3 * (1.0f / 3.0f);
        u1 = d1 - a3f; u2 = d2r - a3f; float u3 = d3 - a3f;
        acc[3] += a3f; acc[4] += sqrtf((u1 * u1 + u2 * u2 + u3 * u3) * 0.5f); acc[5] += d1;
        // k=4
        const float s4 = s3 + d4, a4f = 0.25f * s4;
        u1 = d1 - a4f; u2 = d2r - a4f; u3 = d3 - a4f; const float u4 = d4 - a4f;
        acc[6] += a4f;
        acc[7] += sqrtf((u1 * u1 + u2 * u2 + u3 * u3 + u4 * u4) * (1.0f / 3.0f));
        acc[8] += d1;
    }

    // combine even/odd frame streams
#pragma unroll
    for (int f = 0; f < 9; ++f) acc[f] += __shfl_xor(acc[f], 32, 64);

    // plain (non-atomic) partial store: ws[gw][f][j]
    if (act && half == 0) {
        float* op = ws + (size_t)gw * 225;
#pragma unroll
        for (int f = 0; f < 9; ++f) op[f * NJ + jj] = acc[f];
    }
}

__global__ __launch_bounds__(BLOCKSZ) void reduce_kernel(
        const float* __restrict__ ws, float* __restrict__ out) {
    const int i = blockIdx.x * blockDim.x + threadIdx.x;
    if (i >= NB * NJ * 9) return;
    const int b = i / 225;
    const int r = i - b * 225;
    float s = 0.0f;
#pragma unroll
    for (int c = 0; c < CPB; ++c) s += ws[(size_t)(b * CPB + c) * 225 + r];
    const int f = r / NJ;
    const int j = r - f * NJ;
    out[b * 225 + j * 9 + f] = s * (1.0f / (float)NT);
}

extern "C" void kernel_launch(void* const* d_in, const int* in_sizes, int n_in,
                              void* d_out, int out_size, void* d_ws, size_t ws_size,
                              hipStream_t stream) {
    const float* x = (const float*)d_in[0];
    float* out = (float*)d_out;
    float* ws = (float*)d_ws;   // NW * 225 floats = 3.456 MB

    knn_partial_kernel<<<NW / WAVES, BLOCKSZ, 0, stream>>>(x, ws);
    reduce_kernel<<<(NB * NJ * 9 + BLOCKSZ - 1) / BLOCKSZ, BLOCKSZ, 0, stream>>>(ws, out);
}

// Round 4
// 76.263 us; speedup vs baseline: 1.3032x; 1.0251x over previous
//
#include <hip/hip_runtime.h>
#include <cfloat>

// x: (B=256, T=150, J=25, 3) fp32 -> out: (B, J, 9) fp32
// Per frame: pairwise dists among 25 joints; per joint the 4 smallest
// non-self distances d1<=d2<=d3<=d4 feed [avg,std(ddof=1),min] for
// k=2,3,4 (k=2,3,4 all come from the same sorted-4 prefix); mean over T.
#define NB 256
#define NT 150
#define NJ 25
#define CHUNK 6             // frames per wave (even, divides NT)
#define CPB (NT / CHUNK)    // 25 chunks per batch element
#define WAVES 4
#define BLOCKSZ 256
#define NW (NB * CPB)       // 6400 partial slots, 225 floats each -> 5.76 MB ws

// fast sqrt: direct v_sqrt_f32, no IEEE fixup (inputs are benign magnitudes)
#define FSQRT(x) __builtin_amdgcn_sqrtf(x)

// sorted ascending insert of v into (s0<=s1<=s2<=s3); only min kept at last step
#define INS4(s0, s1, s2, s3, v)                                   \
    {                                                             \
        float m_;                                                 \
        m_ = fminf(s0, v); v = fmaxf(s0, v); s0 = m_;             \
        m_ = fminf(s1, v); v = fmaxf(s1, v); s1 = m_;             \
        m_ = fminf(s2, v); v = fmaxf(s2, v); s2 = m_;             \
        s3 = fminf(s3, v);                                        \
    }

// __launch_bounds__(256,4): cap regalloc ~128 VGPR -> >=4 waves/SIMD resident
__global__ __launch_bounds__(BLOCKSZ, 4) void knn_partial_kernel(
        const float* __restrict__ x, float* __restrict__ ws) {
    __shared__ float4 spos[WAVES][CHUNK][NJ];   // 9.6 KB/block, read as b128 broadcast

    const int tid  = threadIdx.x;
    const int wave = tid >> 6;
    const int lane = tid & 63;
    const int half = lane >> 5;     // which frame of each pair
    const int jj   = lane & 31;     // joint id within half
    const bool act = (jj < NJ);

    const int gw = blockIdx.x * WAVES + wave;   // [0, NW)
    const int b  = gw / CPB;
    const int c  = gw - b * CPB;
    const int t0 = c * CHUNK;

    // ---- stage the chunk (CHUNK frames x 25 joints), packed -> padded float4 ----
    const float* src = x + (size_t)(b * NT + t0) * NJ * 3;
    for (int p = lane; p < CHUNK * NJ; p += 64) {
        const int f = p / NJ;
        const int j = p - f * NJ;
        const float* s = src + p * 3;
        spos[wave][f][j] = make_float4(s[0], s[1], s[2], 0.0f);
    }
    __syncthreads();   // single barrier; LDS read-only afterwards

    float acc[9];
#pragma unroll
    for (int f = 0; f < 9; ++f) acc[f] = 0.0f;

#pragma unroll 1
    for (int p = 0; p < CHUNK / 2; ++p) {
        const int fr = 2 * p + half;
        const float4 own = spos[wave][fr][act ? jj : 0];

        // two parallel sorted-4 chains over SQUARED distances, candidates
        // read straight from LDS (2 broadcast addrs/wave -> conflict-free,
        // compiler pipelines the ds_read_b128s; no 100-VGPR register batch)
        float a0 = FLT_MAX, a1 = FLT_MAX, a2 = FLT_MAX, a3 = FLT_MAX;
        float e0 = FLT_MAX, e1 = FLT_MAX, e2 = FLT_MAX, e3 = FLT_MAX;
#pragma unroll
        for (int i = 0; i < 13; ++i) {
            const float4 q = spos[wave][fr][i];
            const float dx = q.x - own.x, dy = q.y - own.y, dz = q.z - own.z;
            float d2 = dx * dx + dy * dy + dz * dz;
            d2 = (i == jj) ? FLT_MAX : d2;     // exclude self
            INS4(a0, a1, a2, a3, d2);
        }
#pragma unroll
        for (int i = 13; i < NJ; ++i) {
            const float4 q = spos[wave][fr][i];
            const float dx = q.x - own.x, dy = q.y - own.y, dz = q.z - own.z;
            float d2 = dx * dx + dy * dy + dz * dz;
            d2 = (i == jj) ? FLT_MAX : d2;
            INS4(e0, e1, e2, e3, d2);
        }
        // bitonic merge: 4 smallest of (a ++ reverse(e)), then sort them
        const float l0 = fminf(a0, e3), l1 = fminf(a1, e2);
        const float l2 = fminf(a2, e1), l3 = fminf(a3, e0);
        const float m0 = fminf(l0, l2), m2 = fmaxf(l0, l2);
        const float m1 = fminf(l1, l3), m3 = fmaxf(l1, l3);
        const float r0 = fminf(m0, m1), r1 = fmaxf(m0, m1);
        const float r2 = fminf(m2, m3), r3 = fmaxf(m2, m3);

        const float d1 = FSQRT(r0), d2r = FSQRT(r1);
        const float d3 = FSQRT(r2), d4 = FSQRT(r3);

        // std via  var_k = (Sum d^2 - k*mean^2)/(k-1)  -- uses pre-sqrt r's
        const float rs2 = r0 + r1, rs3 = rs2 + r2, rs4 = rs3 + r3;
        // k=2
        const float s2 = d1 + d2r, a2f = 0.5f * s2;
        acc[0] += a2f;
        acc[1] += FSQRT(fmaxf(rs2 - 2.0f * a2f * a2f, 0.0f));
        acc[2] += d1;
        // k=3
        const float s3 = s2 + d3, a3f = s3 * (1.0f / 3.0f);
        acc[3] += a3f;
        acc[4] += FSQRT(fmaxf((rs3 - 3.0f * a3f * a3f) * 0.5f, 0.0f));
        acc[5] += d1;
        // k=4
        const float s4 = s3 + d4, a4f = 0.25f * s4;
        acc[6] += a4f;
        acc[7] += FSQRT(fmaxf((rs4 - 4.0f * a4f * a4f) * (1.0f / 3.0f), 0.0f));
        acc[8] += d1;
    }

    // combine even/odd frame streams
#pragma unroll
    for (int f = 0; f < 9; ++f) acc[f] += __shfl_xor(acc[f], 32, 64);

    // plain coalesced partial store: ws[gw][f][j]
    if (act && half == 0) {
        float* op = ws + (size_t)gw * 225;
#pragma unroll
        for (int f = 0; f < 9; ++f) op[f * NJ + jj] = acc[f];
    }
}

__global__ __launch_bounds__(BLOCKSZ) void reduce_kernel(
        const float* __restrict__ ws, float* __restrict__ out) {
    const int i = blockIdx.x * blockDim.x + threadIdx.x;
    if (i >= NB * NJ * 9) return;
    const int b = i / 225;
    const int r = i - b * 225;
    float s = 0.0f;
#pragma unroll
    for (int c = 0; c < CPB; ++c) s += ws[(size_t)(b * CPB + c) * 225 + r];
    const int f = r / NJ;
    const int j = r - f * NJ;
    out[b * 225 + j * 9 + f] = s * (1.0f / (float)NT);
}

extern "C" void kernel_launch(void* const* d_in, const int* in_sizes, int n_in,
                              void* d_out, int out_size, void* d_ws, size_t ws_size,
                              hipStream_t stream) {
    const float* x = (const float*)d_in[0];
    float* out = (float*)d_out;
    float* ws = (float*)d_ws;   // NW * 225 floats = 5.76 MB

    knn_partial_kernel<<<NW / WAVES, BLOCKSZ, 0, stream>>>(x, ws);
    reduce_kernel<<<(NB * NJ * 9 + BLOCKSZ - 1) / BLOCKSZ, BLOCKSZ, 0, stream>>>(ws, out);
}